// Round 2
// baseline (289.257 us; speedup 1.0000x reference)
//
#include <hip/hip_runtime.h>
#include <hip/hip_bf16.h>
#include <cstdint>
#include <cstddef>

// BAP: out0[b,m,c] = (1/HW) * sum_hw feat[b,c,hw] * sigmoid(raw[b,m,hw])
//      out1[b,m,hw] = sigmoid(raw[b,m,hw])
// B=16, C=1024, M=32, H*W=1024.  ~70 MB traffic -> HBM floor ~11 us.
// ROUND 2: assumption-free fp32 VALU version (no MFMA) to isolate the
// R1 values-wrong failure (0.197 > 2*max|ref| => not a layout permutation).

#define BB 16
#define CC 1024
#define MM 32
#define HW 1024

typedef __attribute__((ext_vector_type(4))) float f32x4;

// ---------------- kernel 1: sigmoid (unchanged from R1) ----------------
__global__ __launch_bounds__(256) void sigmoid_kernel(
    const float* __restrict__ raw, float* __restrict__ out1)
{
    int i = blockIdx.x * 256 + threadIdx.x;          // one float4 per thread
    f32x4 v = reinterpret_cast<const f32x4*>(raw)[i];
    f32x4 s;
#pragma unroll
    for (int j = 0; j < 4; ++j)
        s[j] = 1.0f / (1.0f + __expf(-v[j]));
    reinterpret_cast<f32x4*>(out1)[i] = s;
}

// ---------------- kernel 2: fp32 contraction, no MFMA ----------------
// lane = m + 32*chalf. Each half-wave (32 m-lanes) owns ONE c column:
//   - feat[b][c][k] load: same address across the half-wave (broadcast),
//     each feat element read exactly once chip-wide (64 MB HBM, optimal).
//   - att[b][m][k] load: 32 distinct 4KB-strided per-lane sequential
//     streams (L1-buffered).
// Scalar accumulator per thread -> no cross-lane reduction, no LDS.
__global__ __launch_bounds__(256) void bap_pool_valu(
    const float* __restrict__ feat,   // [B][C][HW]
    const float* __restrict__ att,    // [B][M][HW] fp32 (sigmoid output)
    float* __restrict__ out0)         // [B][M][C]
{
    const int b     = blockIdx.x >> 7;     // 2048 blocks = 16 b * 128 c-groups
    const int c8    = blockIdx.x & 127;    // 8 c per block
    const int lane  = threadIdx.x & 63;
    const int wave  = threadIdx.x >> 6;    // 0..3
    const int m     = lane & 31;
    const int chalf = lane >> 5;           // 0..1
    const int c     = c8 * 8 + wave * 2 + chalf;

    const float* fr = feat + ((size_t)(b * CC + c)) * HW;
    const float* ar = att  + ((size_t)(b * MM + m)) * HW;

    float acc = 0.f;
    for (int k0 = 0; k0 < HW; k0 += 16) {
        f32x4 f0 = *reinterpret_cast<const f32x4*>(fr + k0);
        f32x4 f1 = *reinterpret_cast<const f32x4*>(fr + k0 + 4);
        f32x4 f2 = *reinterpret_cast<const f32x4*>(fr + k0 + 8);
        f32x4 f3 = *reinterpret_cast<const f32x4*>(fr + k0 + 12);
        f32x4 a0 = *reinterpret_cast<const f32x4*>(ar + k0);
        f32x4 a1 = *reinterpret_cast<const f32x4*>(ar + k0 + 4);
        f32x4 a2 = *reinterpret_cast<const f32x4*>(ar + k0 + 8);
        f32x4 a3 = *reinterpret_cast<const f32x4*>(ar + k0 + 12);
#pragma unroll
        for (int j = 0; j < 4; ++j) {
            acc += f0[j] * a0[j];
            acc += f1[j] * a1[j];
            acc += f2[j] * a2[j];
            acc += f3[j] * a3[j];
        }
    }

    out0[(size_t)b * MM * CC + (size_t)m * CC + c] = acc * (1.0f / (float)HW);
}

extern "C" void kernel_launch(void* const* d_in, const int* in_sizes, int n_in,
                              void* d_out, int out_size, void* d_ws, size_t ws_size,
                              hipStream_t stream)
{
    const float* feat = (const float*)d_in[0];   // [16,1024,32,32]
    const float* raw  = (const float*)d_in[1];   // [16,32,32,32]
    float* out0 = (float*)d_out;                          // [16,32,1024]
    float* out1 = out0 + (size_t)BB * MM * HW;            // [16,32,32,32]

    // sigmoid: 524288 elems / 4 per thread = 131072 threads
    sigmoid_kernel<<<512, 256, 0, stream>>>(raw, out1);
    // contraction: 16 b * 128 c-groups = 2048 blocks, 256 threads
    bap_pool_valu<<<2048, 256, 0, stream>>>(feat, out1, out0);
}

// Round 3
// 57.737 us; speedup vs baseline: 5.0099x; 5.0099x over previous
//
#include <hip/hip_runtime.h>
#include <cstdint>
#include <cstddef>

// BAP: out0[b,m,c] = (1/HW) * sum_k feat[b,c,k] * sigmoid(raw[b,m,k])
//      out1[b,m,k] = sigmoid(raw[b,m,k])
// B=16, C=1024, M=32, K=H*W=1024. Memory-bound: ~70MB traffic, floor ~11us.
// R3: coalesced tiled VALU GEMM (R2 was TA/address-divergence bound, 294us).

#define BB 16
#define CC 1024
#define MM 32
#define HW 1024

#define TC   128              // c-rows per block tile
#define TK   64               // k per LDS stage
#define KSPL 4                // k-split factor
#define KPB  (HW / KSPL)      // 256 k per block

typedef __attribute__((ext_vector_type(4))) float f32x4;

// ---------------- kernel 1: sigmoid + zero out0 ----------------
// 512 blocks x 256 thr, one f32x4 per thread covers both regions (both 524288).
__global__ __launch_bounds__(256) void sigmoid_zero_kernel(
    const float* __restrict__ raw, float* __restrict__ out0,
    float* __restrict__ out1)
{
    int i = blockIdx.x * 256 + threadIdx.x;
    f32x4 v = reinterpret_cast<const f32x4*>(raw)[i];
    f32x4 s;
#pragma unroll
    for (int j = 0; j < 4; ++j)
        s[j] = 1.0f / (1.0f + __expf(-v[j]));
    reinterpret_cast<f32x4*>(out1)[i] = s;
    reinterpret_cast<f32x4*>(out0)[i] = (f32x4){0.f, 0.f, 0.f, 0.f};
}

// ---------------- kernel 2: tiled contraction ----------------
// Grid: 512 = 16 b * 8 c-tiles * 4 k-splits. 256 threads (4 waves).
// feat tile [TC][TK] in LDS, XOR-swizzled at f32x4-slot granularity:
//   stored slot' = slot ^ ((row>>2)&15)   (same involution write & read)
// -> coalesced 16B global reads, conflict-free b128 LDS writes AND reads.
// att tile [MM][TK] linear (compute reads are 2-address broadcasts, free).
// Thread tile 4m x 4c in registers; fp32 atomicAdd combine over k-splits.
__global__ __launch_bounds__(256) void bap_tile(
    const float* __restrict__ feat,   // [B][C][HW]
    const float* __restrict__ att,    // [B][M][HW]
    float* __restrict__ out0)         // [B][M][C]
{
    __shared__ float fsh[TC][TK];     // 32 KB, swizzled slots
    __shared__ float ash[MM][TK];     // 8 KB, linear

    const int t  = threadIdx.x;
    const int b  = blockIdx.x >> 5;          // /32 -> 0..15
    const int ct = (blockIdx.x >> 2) & 7;    // c-tile 0..7
    const int kh = blockIdx.x & 3;           // k-split 0..3
    const int cbase = ct * TC;
    const int kbase = kh * KPB;

    const int mt = t >> 5;       // 0..7  -> m0 = 4*mt
    const int cc = t & 31;       // 0..31 -> c0 = 4*cc
    const int m0 = mt * 4;
    const int c0 = cc * 4;

    float acc[4][4] = {};

    for (int k0 = 0; k0 < KPB; k0 += TK) {
        // ---- stage feat: 128 rows x 16 f32x4-slots, 8 per thread ----
#pragma unroll
        for (int i = 0; i < 8; ++i) {
            int id   = t + i * 256;
            int row  = id >> 4;          // 0..127
            int slot = id & 15;          // 0..15
            f32x4 v = *reinterpret_cast<const f32x4*>(
                feat + (size_t)(b * CC + cbase + row) * HW + kbase + k0 + slot * 4);
            int sw = slot ^ ((row >> 2) & 15);
            *reinterpret_cast<f32x4*>(&fsh[row][sw * 4]) = v;
        }
        // ---- stage att: 32 rows x 16 slots, 2 per thread, linear ----
#pragma unroll
        for (int i = 0; i < 2; ++i) {
            int id   = t + i * 256;
            int row  = id >> 4;          // 0..31
            int slot = id & 15;
            f32x4 v = *reinterpret_cast<const f32x4*>(
                att + (size_t)(b * MM + row) * HW + kbase + k0 + slot * 4);
            *reinterpret_cast<f32x4*>(&ash[row][slot * 4]) = v;
        }
        __syncthreads();

        // ---- compute: 16 k-groups of 4, 8 b128 reads + 64 FMA each ----
#pragma unroll 4
        for (int g = 0; g < 16; ++g) {
            f32x4 a[4], f[4];
#pragma unroll
            for (int i = 0; i < 4; ++i)
                a[i] = *reinterpret_cast<const f32x4*>(&ash[m0 + i][g * 4]);
#pragma unroll
            for (int j = 0; j < 4; ++j) {
                int sw = g ^ (((c0 + j) >> 2) & 15);
                f[j] = *reinterpret_cast<const f32x4*>(&fsh[c0 + j][sw * 4]);
            }
#pragma unroll
            for (int i = 0; i < 4; ++i)
#pragma unroll
                for (int j = 0; j < 4; ++j)
#pragma unroll
                    for (int x = 0; x < 4; ++x)
                        acc[i][j] += a[i][x] * f[j][x];
        }
        __syncthreads();
    }

    const float sc = 1.0f / (float)HW;
#pragma unroll
    for (int i = 0; i < 4; ++i)
#pragma unroll
        for (int j = 0; j < 4; ++j)
            atomicAdd(out0 + (size_t)b * MM * CC + (size_t)(m0 + i) * CC
                           + cbase + c0 + j,
                      acc[i][j] * sc);
}

extern "C" void kernel_launch(void* const* d_in, const int* in_sizes, int n_in,
                              void* d_out, int out_size, void* d_ws, size_t ws_size,
                              hipStream_t stream)
{
    const float* feat = (const float*)d_in[0];   // [16,1024,32,32]
    const float* raw  = (const float*)d_in[1];   // [16,32,32,32]
    float* out0 = (float*)d_out;                           // [16,32,1024]
    float* out1 = out0 + (size_t)BB * MM * HW;             // [16,32,32,32]

    // sigmoid + zero the accumulation target (stream order protects atomics)
    sigmoid_zero_kernel<<<512, 256, 0, stream>>>(raw, out0, out1);
    // tiled contraction: 16 b * 8 c-tiles * 4 k-splits = 512 blocks
    bap_tile<<<512, 256, 0, stream>>>(feat, out1, out0);
}